// Round 1
// baseline (427.924 us; speedup 1.0000x reference)
//
#include <hip/hip_runtime.h>

// Quanvolution: 8x1x128x128 input, K=3, STRIDE=2 -> 63x63 patches per image,
// 9-qubit statevector sim per patch, output (8, 9, 63, 63) PauliZ expvals.
//
// Layout: one wave (64 lanes) per patch. 512 amplitudes -> 8 complex per lane.
// Amplitude index bits: [2:0] = register slot r, [8:3] = lane id.
// Qubit q == bit q of amplitude index. Qubits 0-2: in-register gates.
// Qubits 3-8: cross-lane gates via __shfl_xor (no LDS arrays, no barriers).

namespace {

constexpr int OUT_HW = 63;
constexpr int PPB = 4;                                  // waves (patches) per block
constexpr int N_PATCH_TOTAL = 8 * OUT_HW * OUT_HW;      // 31752 == 7938 * 4

// General 2x2 unitary on qubit Q. u** are per-lane-uniform coefficients.
template<int Q>
__device__ __forceinline__ void gate1q(float (&ar)[8], float (&ai)[8], int lane,
                                       float u00r, float u00i, float u01r, float u01i,
                                       float u10r, float u10i, float u11r, float u11i)
{
    if constexpr (Q < 3) {
        constexpr int qm = 1 << Q;
        #pragma unroll
        for (int r = 0; r < 8; ++r) {
            if (!(r & qm)) {
                const int r1 = r | qm;
                const float xr = ar[r],  xi = ai[r];
                const float yr = ar[r1], yi = ai[r1];
                ar[r]  = u00r*xr - u00i*xi + u01r*yr - u01i*yi;
                ai[r]  = u00r*xi + u00i*xr + u01r*yi + u01i*yr;
                ar[r1] = u10r*xr - u10i*xi + u11r*yr - u11i*yi;
                ai[r1] = u10r*xi + u10i*xr + u11r*yi + u11i*yr;
            }
        }
    } else {
        constexpr int lm = 1 << (Q - 3);
        const int bit = (lane >> (Q - 3)) & 1;
        const float csr = bit ? u11r : u00r;   // coefficient of self
        const float csi = bit ? u11i : u00i;
        const float cpr = bit ? u10r : u01r;   // coefficient of partner
        const float cpi = bit ? u10i : u01i;
        #pragma unroll
        for (int r = 0; r < 8; ++r) {
            const float br = __shfl_xor(ar[r], lm, 64);
            const float bi = __shfl_xor(ai[r], lm, 64);
            const float nr = csr*ar[r] - csi*ai[r] + cpr*br - cpi*bi;
            const float ni = csr*ai[r] + csi*ar[r] + cpr*bi + cpi*br;
            ar[r] = nr; ai[r] = ni;
        }
    }
}

// CNOT control C target T: new[i] = old[i ^ (bit_C(i) << T)] — pure permutation.
template<int C, int T>
__device__ __forceinline__ void cnot(float (&ar)[8], float (&ai)[8], int lane)
{
    if constexpr (C < 3 && T < 3) {
        constexpr int cm = 1 << C, tm = 1 << T;
        #pragma unroll
        for (int r = 0; r < 8; ++r) {
            if ((r & cm) && !(r & tm)) {
                const int r1 = r | tm;
                const float tr = ar[r], ti = ai[r];
                ar[r] = ar[r1]; ai[r] = ai[r1];
                ar[r1] = tr;    ai[r1] = ti;
            }
        }
    } else if constexpr (C < 3) {            // T is a lane bit
        constexpr int cm = 1 << C, lm = 1 << (T - 3);
        #pragma unroll
        for (int r = 0; r < 8; ++r) {
            if (r & cm) {                    // partner's reg r also has bit_C=1: pure exchange
                ar[r] = __shfl_xor(ar[r], lm, 64);
                ai[r] = __shfl_xor(ai[r], lm, 64);
            }
        }
    } else if constexpr (T < 3) {            // C lane bit, T register bit: predicated reg swap
        constexpr int tm = 1 << T;
        const bool cb = ((lane >> (C - 3)) & 1) != 0;
        #pragma unroll
        for (int r = 0; r < 8; ++r) {
            if (!(r & tm)) {
                const int r1 = r | tm;
                const float t0r = cb ? ar[r1] : ar[r];
                const float t0i = cb ? ai[r1] : ai[r];
                const float t1r = cb ? ar[r]  : ar[r1];
                const float t1i = cb ? ai[r]  : ai[r1];
                ar[r]  = t0r; ai[r]  = t0i;
                ar[r1] = t1r; ai[r1] = t1i;
            }
        }
    } else {                                  // both lane bits: exchange among cb==1 lanes
        constexpr int lm = 1 << (T - 3);
        const bool cb = ((lane >> (C - 3)) & 1) != 0;
        #pragma unroll
        for (int r = 0; r < 8; ++r) {
            const float pr = __shfl_xor(ar[r], lm, 64);
            const float pq = __shfl_xor(ai[r], lm, 64);
            ar[r] = cb ? pr : ar[r];
            ai[r] = cb ? pq : ai[r];
        }
    }
}

// Precompute the 18 Rot matrices (weights are shared across all patches).
// rot[(l*9+q)*8 + {0..7}] = u00.re, u00.im, u01.re, u01.im, u10.re, u10.im, u11.re, u11.im
__global__ void rot_precomp_kernel(const float* __restrict__ w, float* __restrict__ rot)
{
    const int i = threadIdx.x;
    if (i >= 18) return;
    const float phi = w[i*3 + 0], theta = w[i*3 + 1], omega = w[i*3 + 2];
    const float ct = cosf(0.5f * theta), st = sinf(0.5f * theta);
    const float apo = 0.5f * (phi + omega), amo = 0.5f * (phi - omega);
    const float ca = cosf(apo), sa = sinf(apo);
    const float cm = cosf(amo), sm = sinf(amo);
    float* m = rot + i * 8;
    m[0] =  ca * ct; m[1] = -sa * ct;   // u00 = e^{-i(phi+omega)/2} cos(theta/2)
    m[2] = -cm * st; m[3] = -sm * st;   // u01 = -e^{+i(phi-omega)/2} sin(theta/2)
    m[4] =  cm * st; m[5] = -sm * st;   // u10 = e^{-i(phi-omega)/2} sin(theta/2)
    m[6] =  ca * ct; m[7] =  sa * ct;   // u11 = e^{+i(phi+omega)/2} cos(theta/2)
}

#define APPLY_RX(q)  gate1q<q>(ar, ai, lane, cs[q], 0.f, 0.f, -sn[q], 0.f, -sn[q], cs[q], 0.f);
#define APPLY_ROT(q) gate1q<q>(ar, ai, lane, m[8*(q)+0], m[8*(q)+1], m[8*(q)+2], m[8*(q)+3], \
                                             m[8*(q)+4], m[8*(q)+5], m[8*(q)+6], m[8*(q)+7]);

__global__ __launch_bounds__(PPB * 64) void qconv_kernel(
    const float* __restrict__ x,      // (8, 1, 128, 128)
    const float* __restrict__ rot,    // (2, 9, 8) precomputed Rot matrices
    float* __restrict__ out)          // (8, 9, 63, 63)
{
    const int lane  = threadIdx.x & 63;
    const int wv    = threadIdx.x >> 6;
    const int patch = blockIdx.x * PPB + wv;
    if (patch >= N_PATCH_TOTAL) return;          // wave-uniform

    const int b   = patch / (OUT_HW * OUT_HW);
    const int rem = patch - b * (OUT_HW * OUT_HW);
    const int oy  = rem / OUT_HW;
    const int ox  = rem - oy * OUT_HW;

    const float* xp = x + b * 16384 + (oy * 2) * 128 + (ox * 2);

    // RX half-angle sin/cos for this patch's 9 angles
    float cs[9], sn[9];
    #pragma unroll
    for (int q = 0; q < 9; ++q) {
        const float a = xp[(q / 3) * 128 + (q % 3)];
        __sincosf(0.5f * a, &sn[q], &cs[q]);
        // use accurate versions to be safe:
        sn[q] = sinf(0.5f * a);
        cs[q] = cosf(0.5f * a);
    }

    // |0...0>
    float ar[8], ai[8];
    #pragma unroll
    for (int r = 0; r < 8; ++r) { ar[r] = 0.f; ai[r] = 0.f; }
    if (lane == 0) ar[0] = 1.0f;

    // Encoding layer: RX(angle_q) on qubit q
    APPLY_RX(0) APPLY_RX(1) APPLY_RX(2) APPLY_RX(3) APPLY_RX(4)
    APPLY_RX(5) APPLY_RX(6) APPLY_RX(7) APPLY_RX(8)

    // 2 outer iterations of [Rot(l=0); CNOT ring r=1; Rot(l=1); CNOT ring r=2]
    #pragma unroll
    for (int outer = 0; outer < 2; ++outer) {
        {   // l = 0
            const float* m = rot;
            APPLY_ROT(0) APPLY_ROT(1) APPLY_ROT(2) APPLY_ROT(3) APPLY_ROT(4)
            APPLY_ROT(5) APPLY_ROT(6) APPLY_ROT(7) APPLY_ROT(8)
            cnot<0,1>(ar, ai, lane); cnot<1,2>(ar, ai, lane); cnot<2,3>(ar, ai, lane);
            cnot<3,4>(ar, ai, lane); cnot<4,5>(ar, ai, lane); cnot<5,6>(ar, ai, lane);
            cnot<6,7>(ar, ai, lane); cnot<7,8>(ar, ai, lane); cnot<8,0>(ar, ai, lane);
        }
        {   // l = 1
            const float* m = rot + 72;
            APPLY_ROT(0) APPLY_ROT(1) APPLY_ROT(2) APPLY_ROT(3) APPLY_ROT(4)
            APPLY_ROT(5) APPLY_ROT(6) APPLY_ROT(7) APPLY_ROT(8)
            cnot<0,2>(ar, ai, lane); cnot<1,3>(ar, ai, lane); cnot<2,4>(ar, ai, lane);
            cnot<3,5>(ar, ai, lane); cnot<4,6>(ar, ai, lane); cnot<5,7>(ar, ai, lane);
            cnot<6,8>(ar, ai, lane); cnot<7,0>(ar, ai, lane); cnot<8,1>(ar, ai, lane);
        }
    }

    // PauliZ expvals: e[q] = sum_i |amp_i|^2 * (-1)^{bit_q(i)}
    float p[8];
    float total = 0.f;
    #pragma unroll
    for (int r = 0; r < 8; ++r) {
        p[r] = ar[r]*ar[r] + ai[r]*ai[r];
        total += p[r];
    }
    float e[9];
    #pragma unroll
    for (int q = 0; q < 3; ++q) {
        float acc = 0.f;
        #pragma unroll
        for (int r = 0; r < 8; ++r)
            acc += ((r >> q) & 1) ? -p[r] : p[r];
        e[q] = acc;
    }
    #pragma unroll
    for (int q = 3; q < 9; ++q)
        e[q] = ((lane >> (q - 3)) & 1) ? -total : total;

    // Butterfly reduce across the 64 lanes
    #pragma unroll
    for (int mk = 1; mk < 64; mk <<= 1) {
        #pragma unroll
        for (int q = 0; q < 9; ++q)
            e[q] += __shfl_xor(e[q], mk, 64);
    }

    if (lane == 0) {
        float* op = out + (b * 9) * (OUT_HW * OUT_HW) + oy * OUT_HW + ox;
        #pragma unroll
        for (int q = 0; q < 9; ++q)
            op[q * (OUT_HW * OUT_HW)] = e[q];
    }
}

} // anonymous namespace

extern "C" void kernel_launch(void* const* d_in, const int* in_sizes, int n_in,
                              void* d_out, int out_size, void* d_ws, size_t ws_size,
                              hipStream_t stream)
{
    const float* x = (const float*)d_in[0];   // (8,1,128,128) float32
    const float* w = (const float*)d_in[1];   // (2,9,3) float32
    float* rot = (float*)d_ws;                // 144 floats scratch
    float* out = (float*)d_out;               // (8,9,63,63) float32

    rot_precomp_kernel<<<1, 64, 0, stream>>>(w, rot);
    qconv_kernel<<<N_PATCH_TOTAL / PPB, PPB * 64, 0, stream>>>(x, rot, out);
}

// Round 3
// 325.442 us; speedup vs baseline: 1.3149x; 1.3149x over previous
//
#include <hip/hip_runtime.h>

// Quanvolution: 8x1x128x128 input, K=3, STRIDE=2 -> 63x63 patches per image,
// 9-qubit statevector sim per patch, output (8, 9, 63, 63) PauliZ expvals.
//
// Layout: one wave (64 lanes) per patch. 512 amplitudes -> 8 complex per lane.
// Amplitude index bits: [2:0] = register slot r, [8:3] = lane id.
// Qubit q == bit q of amplitude index. Qubits 0-2: in-register gates.
// Qubits 3-8: cross-lane gates via ds_swizzle (mask<32) / ds_bpermute (mask 32).
//
// R3: fixes R2's ring1 gather mask. Composed gather for CNOTs (2,3)..(7,8) is
//   g'(i) = i ^ ((bits 2..7 of i) << 1)  ->  src_lane = lane ^ ((lane&31)<<1) ^ reg_bit2
// R2 used (lane&15)<<1, silently dropping CNOT(7,8). Ring2's (lane&15)<<2 is
// correct: g'(i) = i ^ ((bits 1..6 of i) << 2), lane-bit sources are 0..3 only.

namespace {

constexpr int OUT_HW = 63;
constexpr int PPB = 4;                                  // waves (patches) per block
constexpr int N_PATCH_TOTAL = 8 * OUT_HW * OUT_HW;      // 31752 == 7938 * 4

__device__ __forceinline__ float bperm(int addr_bytes, float v) {
    return __int_as_float(__builtin_amdgcn_ds_bpermute(addr_bytes, __float_as_int(v)));
}

// xor-shuffle across lanes: ds_swizzle for mask<32 (no addr VGPR), bpermute for 32
template<int M>
__device__ __forceinline__ float shflx(float v, int lane) {
    if constexpr (M < 32)
        return __int_as_float(__builtin_amdgcn_ds_swizzle(__float_as_int(v),
                                                          0x1F | (M << 10)));
    else
        return bperm((lane << 2) ^ 128, v);
}

// General 2x2 unitary on qubit Q. u** are wave-uniform (but per-patch) coeffs.
template<int Q>
__device__ __forceinline__ void gate1q(float (&ar)[8], float (&ai)[8], int lane,
                                       float u00r, float u00i, float u01r, float u01i,
                                       float u10r, float u10i, float u11r, float u11i)
{
    if constexpr (Q < 3) {
        constexpr int qm = 1 << Q;
        #pragma unroll
        for (int r = 0; r < 8; ++r) {
            if (!(r & qm)) {
                const int r1 = r | qm;
                const float xr = ar[r],  xi = ai[r];
                const float yr = ar[r1], yi = ai[r1];
                ar[r]  = u00r*xr - u00i*xi + u01r*yr - u01i*yi;
                ai[r]  = u00r*xi + u00i*xr + u01r*yi + u01i*yr;
                ar[r1] = u10r*xr - u10i*xi + u11r*yr - u11i*yi;
                ai[r1] = u10r*xi + u10i*xr + u11r*yi + u11i*yr;
            }
        }
    } else {
        constexpr int lm = 1 << (Q - 3);
        const int bit = (lane >> (Q - 3)) & 1;
        const float csr = bit ? u11r : u00r;   // coefficient of self
        const float csi = bit ? u11i : u00i;
        const float cpr = bit ? u10r : u01r;   // coefficient of partner
        const float cpi = bit ? u10i : u01i;
        #pragma unroll
        for (int r = 0; r < 8; ++r) {
            const float br = shflx<lm>(ar[r], lane);
            const float bi = shflx<lm>(ai[r], lane);
            const float nr = csr*ar[r] - csi*ai[r] + cpr*br - cpi*bi;
            const float ni = csr*ai[r] + csi*ar[r] + cpr*bi + cpi*br;
            ar[r] = nr; ai[r] = ni;
        }
    }
}

// CNOT control C target T: new[i] = old[i ^ (bit_C(i) << T)].
// Only reg-reg (free renaming) and lane-ctrl/reg-tgt (cndmask) variants are
// used; lane-target CNOTs are folded into the ring gathers below.
template<int C, int T>
__device__ __forceinline__ void cnot(float (&ar)[8], float (&ai)[8], int lane)
{
    if constexpr (C < 3 && T < 3) {
        constexpr int cm = 1 << C, tm = 1 << T;
        #pragma unroll
        for (int r = 0; r < 8; ++r) {
            if ((r & cm) && !(r & tm)) {
                const int r1 = r | tm;
                const float tr = ar[r], ti = ai[r];
                ar[r] = ar[r1]; ai[r] = ai[r1];
                ar[r1] = tr;    ai[r1] = ti;
            }
        }
    } else if constexpr (T < 3) {            // C lane bit, T register bit
        constexpr int tm = 1 << T;
        const bool cb = ((lane >> (C - 3)) & 1) != 0;
        #pragma unroll
        for (int r = 0; r < 8; ++r) {
            if (!(r & tm)) {
                const int r1 = r | tm;
                const float t0r = cb ? ar[r1] : ar[r];
                const float t0i = cb ? ai[r1] : ai[r];
                const float t1r = cb ? ar[r]  : ar[r1];
                const float t1i = cb ? ai[r]  : ai[r1];
                ar[r]  = t0r; ai[r]  = t0i;
                ar[r1] = t1r; ai[r1] = t1i;
            }
        }
    }
}

// Ring r=1: (0,1)(1,2)(2,3)(3,4)(4,5)(5,6)(6,7)(7,8)(8,0).
// (0,1),(1,2): reg renames. (2,3)..(7,8) compose to
//   src_lane = lane ^ ((lane & 31) << 1) ^ bit2(reg). (8,0): cndmask.
__device__ __forceinline__ void ring1(float (&ar)[8], float (&ai)[8], int lane)
{
    cnot<0,1>(ar, ai, lane);
    cnot<1,2>(ar, ai, lane);
    const int sA = (lane ^ ((lane & 31) << 1)) << 2;
    const int sB = sA ^ 4;                  // ^ lane bit0 (regs with bit2 set)
    #pragma unroll
    for (int r = 0; r < 8; ++r) {
        const int a = (r & 4) ? sB : sA;
        ar[r] = bperm(a, ar[r]);
        ai[r] = bperm(a, ai[r]);
    }
    cnot<8,0>(ar, ai, lane);
}

// Ring r=2: (0,2)(1,3)(2,4)(3,5)(4,6)(5,7)(6,8)(7,0)(8,1).
// (0,2): reg rename. (1,3)..(6,8) compose to
//   src_lane = lane ^ ((lane & 15) << 2) ^ bit1(reg) ^ (bit2(reg)<<1).
// (7,0),(8,1): cndmask.
__device__ __forceinline__ void ring2(float (&ar)[8], float (&ai)[8], int lane)
{
    cnot<0,2>(ar, ai, lane);
    const int s0 = (lane ^ ((lane & 15) << 2)) << 2;
    #pragma unroll
    for (int r = 0; r < 8; ++r) {
        const int a = s0 ^ (((r >> 1) & 1) << 2) ^ (((r >> 2) & 1) << 3);
        ar[r] = bperm(a, ar[r]);
        ai[r] = bperm(a, ai[r]);
    }
    cnot<7,0>(ar, ai, lane);
    cnot<8,1>(ar, ai, lane);
}

// Precompute the 18 Rot matrices (weights shared across all patches).
// rot[(l*9+q)*8 + {0..7}] = u00.re,u00.im,u01.re,u01.im,u10.re,u10.im,u11.re,u11.im
__global__ void rot_precomp_kernel(const float* __restrict__ w, float* __restrict__ rot)
{
    const int i = threadIdx.x;
    if (i >= 18) return;
    const float phi = w[i*3 + 0], theta = w[i*3 + 1], omega = w[i*3 + 2];
    const float ct = cosf(0.5f * theta), st = sinf(0.5f * theta);
    const float apo = 0.5f * (phi + omega), amo = 0.5f * (phi - omega);
    const float ca = cosf(apo), sa = sinf(apo);
    const float cm = cosf(amo), sm = sinf(amo);
    float* m = rot + i * 8;
    m[0] =  ca * ct; m[1] = -sa * ct;   // u00 = e^{-i(phi+omega)/2} cos(th/2)
    m[2] = -cm * st; m[3] = -sm * st;   // u01 = -e^{+i(phi-omega)/2} sin(th/2)
    m[4] =  cm * st; m[5] = -sm * st;   // u10 = e^{-i(phi-omega)/2} sin(th/2)
    m[6] =  ca * ct; m[7] =  sa * ct;   // u11 = e^{+i(phi+omega)/2} cos(th/2)
}

#define APPLY_ROT(q) gate1q<q>(ar, ai, lane, m[8*(q)+0], m[8*(q)+1], m[8*(q)+2], m[8*(q)+3], \
                                             m[8*(q)+4], m[8*(q)+5], m[8*(q)+6], m[8*(q)+7]);

// Fused gate: Rot(l=0,q) * RX(angle_q). RX = [[c, -is],[-is, c]].
#define FUSED_ROT_RX(q) { \
    const float* R = rot + 8*(q); \
    const float c = cs[q], s = sn[q]; \
    const float f00r = c*R[0] + s*R[3], f00i = c*R[1] - s*R[2]; \
    const float f01r = c*R[2] + s*R[1], f01i = c*R[3] - s*R[0]; \
    const float f10r = c*R[4] + s*R[7], f10i = c*R[5] - s*R[6]; \
    const float f11r = c*R[6] + s*R[5], f11i = c*R[7] - s*R[4]; \
    gate1q<q>(ar, ai, lane, f00r, f00i, f01r, f01i, f10r, f10i, f11r, f11i); }

__global__ __launch_bounds__(PPB * 64) void qconv_kernel(
    const float* __restrict__ x,      // (8, 1, 128, 128)
    const float* __restrict__ rot,    // (2, 9, 8) precomputed Rot matrices
    float* __restrict__ out)          // (8, 9, 63, 63)
{
    const int lane  = threadIdx.x & 63;
    const int wv    = threadIdx.x >> 6;
    const int patch = blockIdx.x * PPB + wv;
    if (patch >= N_PATCH_TOTAL) return;          // wave-uniform (never taken)

    const int b   = patch / (OUT_HW * OUT_HW);
    const int rem = patch - b * (OUT_HW * OUT_HW);
    const int oy  = rem / OUT_HW;
    const int ox  = rem - oy * OUT_HW;

    const float* xp = x + b * 16384 + (oy * 2) * 128 + (ox * 2);

    // RX half-angle sin/cos for this patch's 9 angles (fast HW sincos;
    // abs err ~1e-5 << 7.8e-3 threshold)
    float cs[9], sn[9];
    #pragma unroll
    for (int q = 0; q < 9; ++q) {
        const float a = xp[(q / 3) * 128 + (q % 3)];
        __sincosf(0.5f * a, &sn[q], &cs[q]);
    }

    // |0...0>
    float ar[8], ai[8];
    #pragma unroll
    for (int r = 0; r < 8; ++r) { ar[r] = 0.f; ai[r] = 0.f; }
    if (lane == 0) ar[0] = 1.0f;

    // Layer 1: fused RX + Rot(l=0), then ring r=1
    FUSED_ROT_RX(0) FUSED_ROT_RX(1) FUSED_ROT_RX(2) FUSED_ROT_RX(3) FUSED_ROT_RX(4)
    FUSED_ROT_RX(5) FUSED_ROT_RX(6) FUSED_ROT_RX(7) FUSED_ROT_RX(8)
    ring1(ar, ai, lane);
    {   // Layer 2: Rot(l=1), ring r=2
        const float* m = rot + 72;
        APPLY_ROT(0) APPLY_ROT(1) APPLY_ROT(2) APPLY_ROT(3) APPLY_ROT(4)
        APPLY_ROT(5) APPLY_ROT(6) APPLY_ROT(7) APPLY_ROT(8)
        ring2(ar, ai, lane);
    }
    {   // Layer 3: Rot(l=0), ring r=1
        const float* m = rot;
        APPLY_ROT(0) APPLY_ROT(1) APPLY_ROT(2) APPLY_ROT(3) APPLY_ROT(4)
        APPLY_ROT(5) APPLY_ROT(6) APPLY_ROT(7) APPLY_ROT(8)
        ring1(ar, ai, lane);
    }
    {   // Layer 4: Rot(l=1), ring r=2
        const float* m = rot + 72;
        APPLY_ROT(0) APPLY_ROT(1) APPLY_ROT(2) APPLY_ROT(3) APPLY_ROT(4)
        APPLY_ROT(5) APPLY_ROT(6) APPLY_ROT(7) APPLY_ROT(8)
        ring2(ar, ai, lane);
    }

    // PauliZ expvals: e[q] = sum_i |amp_i|^2 * (-1)^{bit_q(i)}
    float p[8];
    float total = 0.f;
    #pragma unroll
    for (int r = 0; r < 8; ++r) {
        p[r] = ar[r]*ar[r] + ai[r]*ai[r];
        total += p[r];
    }
    float e[9];
    #pragma unroll
    for (int q = 0; q < 3; ++q) {
        float acc = 0.f;
        #pragma unroll
        for (int r = 0; r < 8; ++r)
            acc += ((r >> q) & 1) ? -p[r] : p[r];
        e[q] = acc;
    }
    #pragma unroll
    for (int q = 3; q < 9; ++q)
        e[q] = ((lane >> (q - 3)) & 1) ? -total : total;

    // Butterfly reduce across the 64 lanes
    #pragma unroll
    for (int q = 0; q < 9; ++q) e[q] += shflx<1>(e[q], lane);
    #pragma unroll
    for (int q = 0; q < 9; ++q) e[q] += shflx<2>(e[q], lane);
    #pragma unroll
    for (int q = 0; q < 9; ++q) e[q] += shflx<4>(e[q], lane);
    #pragma unroll
    for (int q = 0; q < 9; ++q) e[q] += shflx<8>(e[q], lane);
    #pragma unroll
    for (int q = 0; q < 9; ++q) e[q] += shflx<16>(e[q], lane);
    #pragma unroll
    for (int q = 0; q < 9; ++q) e[q] += shflx<32>(e[q], lane);

    if (lane == 0) {
        float* op = out + (b * 9) * (OUT_HW * OUT_HW) + oy * OUT_HW + ox;
        #pragma unroll
        for (int q = 0; q < 9; ++q)
            op[q * (OUT_HW * OUT_HW)] = e[q];
    }
}

} // anonymous namespace

extern "C" void kernel_launch(void* const* d_in, const int* in_sizes, int n_in,
                              void* d_out, int out_size, void* d_ws, size_t ws_size,
                              hipStream_t stream)
{
    const float* x = (const float*)d_in[0];   // (8,1,128,128) float32
    const float* w = (const float*)d_in[1];   // (2,9,3) float32
    float* rot = (float*)d_ws;                // 144 floats scratch
    float* out = (float*)d_out;               // (8,9,63,63) float32

    rot_precomp_kernel<<<1, 64, 0, stream>>>(w, rot);
    qconv_kernel<<<N_PATCH_TOTAL / PPB, PPB * 64, 0, stream>>>(x, rot, out);
}

// Round 4
// 281.074 us; speedup vs baseline: 1.5225x; 1.1579x over previous
//
#include <hip/hip_runtime.h>

// Quanvolution: 8x1x128x128 input, K=3, STRIDE=2 -> 63x63 patches per image,
// 9-qubit statevector sim per patch, output (8, 9, 63, 63) PauliZ expvals.
//
// Layout: one wave (64 lanes) per patch. 512 amplitudes -> 8 complex per lane.
// Amplitude index bits: [2:0] = register slot r, [8:3] = lane id.
// Qubit q == bit q of amplitude index (LSB convention, consistent across
// gates/CNOTs/measurement so it matches the reference up to relabeling).
//
// R4 changes vs R3 (passed, 318 us):
//  - Product-state construction replaces encode+first-Rot-layer (9 gates incl
//    6 cross-lane ones): amp(p) = prod_q (bit_q(p) ? beta_q : alpha_q), where
//    (alpha,beta) = first column of Rot(l0)*RX. ~340 VALU, 0 DS.
//  - Final CNOT ring absorbed into measurement: rings are GF(2)-linear index
//    permutations; <Z_q> after ring2 = signed parity sum with compile-time
//    masks w_q (row rule w_t ^= w_c over the ring; cross-checked vs Heisenberg
//    pull-back O_0 = Z0Z1Z3Z5Z7). Masks: {0xAB,0x157,0x5,0xA,0x15,0x2A,0x55,
//    0xAA,0x155}.
//  - __launch_bounds__(256, 8): force VGPR<=64 for 8 waves/SIMD.

namespace {

constexpr int OUT_HW = 63;
constexpr int PPB = 4;                                  // waves (patches) per block
constexpr int N_PATCH_TOTAL = 8 * OUT_HW * OUT_HW;      // 31752 == 7938 * 4

__device__ __forceinline__ float bperm(int addr_bytes, float v) {
    return __int_as_float(__builtin_amdgcn_ds_bpermute(addr_bytes, __float_as_int(v)));
}

// xor-shuffle across lanes: ds_swizzle for mask<32 (no addr VGPR), bpermute for 32
template<int M>
__device__ __forceinline__ float shflx(float v, int lane) {
    if constexpr (M < 32)
        return __int_as_float(__builtin_amdgcn_ds_swizzle(__float_as_int(v),
                                                          0x1F | (M << 10)));
    else
        return bperm((lane << 2) ^ 128, v);
}

// General 2x2 unitary on qubit Q. u** are wave-uniform (but per-patch) coeffs.
template<int Q>
__device__ __forceinline__ void gate1q(float (&ar)[8], float (&ai)[8], int lane,
                                       float u00r, float u00i, float u01r, float u01i,
                                       float u10r, float u10i, float u11r, float u11i)
{
    if constexpr (Q < 3) {
        constexpr int qm = 1 << Q;
        #pragma unroll
        for (int r = 0; r < 8; ++r) {
            if (!(r & qm)) {
                const int r1 = r | qm;
                const float xr = ar[r],  xi = ai[r];
                const float yr = ar[r1], yi = ai[r1];
                ar[r]  = u00r*xr - u00i*xi + u01r*yr - u01i*yi;
                ai[r]  = u00r*xi + u00i*xr + u01r*yi + u01i*yr;
                ar[r1] = u10r*xr - u10i*xi + u11r*yr - u11i*yi;
                ai[r1] = u10r*xi + u10i*xr + u11r*yi + u11i*yr;
            }
        }
    } else {
        constexpr int lm = 1 << (Q - 3);
        const int bit = (lane >> (Q - 3)) & 1;
        const float csr = bit ? u11r : u00r;   // coefficient of self
        const float csi = bit ? u11i : u00i;
        const float cpr = bit ? u10r : u01r;   // coefficient of partner
        const float cpi = bit ? u10i : u01i;
        #pragma unroll
        for (int r = 0; r < 8; ++r) {
            const float br = shflx<lm>(ar[r], lane);
            const float bi = shflx<lm>(ai[r], lane);
            const float nr = csr*ar[r] - csi*ai[r] + cpr*br - cpi*bi;
            const float ni = csr*ai[r] + csi*ar[r] + cpr*bi + cpi*br;
            ar[r] = nr; ai[r] = ni;
        }
    }
}

// CNOT control C target T: new[i] = old[i ^ (bit_C(i) << T)].
template<int C, int T>
__device__ __forceinline__ void cnot(float (&ar)[8], float (&ai)[8], int lane)
{
    if constexpr (C < 3 && T < 3) {
        constexpr int cm = 1 << C, tm = 1 << T;
        #pragma unroll
        for (int r = 0; r < 8; ++r) {
            if ((r & cm) && !(r & tm)) {
                const int r1 = r | tm;
                const float tr = ar[r], ti = ai[r];
                ar[r] = ar[r1]; ai[r] = ai[r1];
                ar[r1] = tr;    ai[r1] = ti;
            }
        }
    } else if constexpr (T < 3) {            // C lane bit, T register bit
        constexpr int tm = 1 << T;
        const bool cb = ((lane >> (C - 3)) & 1) != 0;
        #pragma unroll
        for (int r = 0; r < 8; ++r) {
            if (!(r & tm)) {
                const int r1 = r | tm;
                const float t0r = cb ? ar[r1] : ar[r];
                const float t0i = cb ? ai[r1] : ai[r];
                const float t1r = cb ? ar[r]  : ar[r1];
                const float t1i = cb ? ai[r]  : ai[r1];
                ar[r]  = t0r; ai[r]  = t0i;
                ar[r1] = t1r; ai[r1] = t1i;
            }
        }
    }
}

// Ring r=1: (0,1)(1,2)(2,3)(3,4)(4,5)(5,6)(6,7)(7,8)(8,0).
// (0,1),(1,2): reg renames. (2,3)..(7,8) compose to
//   src_lane = lane ^ ((lane & 31) << 1) ^ bit2(reg). (8,0): cndmask.
__device__ __forceinline__ void ring1(float (&ar)[8], float (&ai)[8], int lane)
{
    cnot<0,1>(ar, ai, lane);
    cnot<1,2>(ar, ai, lane);
    const int sA = (lane ^ ((lane & 31) << 1)) << 2;
    const int sB = sA ^ 4;                  // ^ lane bit0 (regs with bit2 set)
    #pragma unroll
    for (int r = 0; r < 8; ++r) {
        const int a = (r & 4) ? sB : sA;
        ar[r] = bperm(a, ar[r]);
        ai[r] = bperm(a, ai[r]);
    }
    cnot<8,0>(ar, ai, lane);
}

// Ring r=2: (0,2)(1,3)(2,4)(3,5)(4,6)(5,7)(6,8)(7,0)(8,1).
// (0,2): reg rename. (1,3)..(6,8) compose to
//   src_lane = lane ^ ((lane & 15) << 2) ^ bit1(reg) ^ (bit2(reg)<<1).
// (7,0),(8,1): cndmask.
__device__ __forceinline__ void ring2(float (&ar)[8], float (&ai)[8], int lane)
{
    cnot<0,2>(ar, ai, lane);
    const int s0 = (lane ^ ((lane & 15) << 2)) << 2;
    #pragma unroll
    for (int r = 0; r < 8; ++r) {
        const int a = s0 ^ (((r >> 1) & 1) << 2) ^ (((r >> 2) & 1) << 3);
        ar[r] = bperm(a, ar[r]);
        ai[r] = bperm(a, ai[r]);
    }
    cnot<7,0>(ar, ai, lane);
    cnot<8,1>(ar, ai, lane);
}

// Precompute the 18 Rot matrices (weights shared across all patches).
// rot[(l*9+q)*8 + {0..7}] = u00.re,u00.im,u01.re,u01.im,u10.re,u10.im,u11.re,u11.im
__global__ void rot_precomp_kernel(const float* __restrict__ w, float* __restrict__ rot)
{
    const int i = threadIdx.x;
    if (i >= 18) return;
    const float phi = w[i*3 + 0], theta = w[i*3 + 1], omega = w[i*3 + 2];
    const float ct = cosf(0.5f * theta), st = sinf(0.5f * theta);
    const float apo = 0.5f * (phi + omega), amo = 0.5f * (phi - omega);
    const float ca = cosf(apo), sa = sinf(apo);
    const float cm = cosf(amo), sm = sinf(amo);
    float* m = rot + i * 8;
    m[0] =  ca * ct; m[1] = -sa * ct;   // u00 = e^{-i(phi+omega)/2} cos(th/2)
    m[2] = -cm * st; m[3] = -sm * st;   // u01 = -e^{+i(phi-omega)/2} sin(th/2)
    m[4] =  cm * st; m[5] = -sm * st;   // u10 = e^{-i(phi-omega)/2} sin(th/2)
    m[6] =  ca * ct; m[7] =  sa * ct;   // u11 = e^{+i(phi+omega)/2} cos(th/2)
}

#define APPLY_ROT(q) gate1q<q>(ar, ai, lane, m[8*(q)+0], m[8*(q)+1], m[8*(q)+2], m[8*(q)+3], \
                                             m[8*(q)+4], m[8*(q)+5], m[8*(q)+6], m[8*(q)+7]);

// sign-apply: v * (-1)^par  (par in {0,1})
__device__ __forceinline__ float sgn_apply(float v, int par) {
    return __int_as_float(__float_as_int(v) ^ (par << 31));
}

__global__ __launch_bounds__(PPB * 64, 8) void qconv_kernel(
    const float* __restrict__ x,      // (8, 1, 128, 128)
    const float* __restrict__ rot,    // (2, 9, 8) precomputed Rot matrices
    float* __restrict__ out)          // (8, 9, 63, 63)
{
    const int lane  = threadIdx.x & 63;
    const int wv    = threadIdx.x >> 6;
    const int patch = blockIdx.x * PPB + wv;
    if (patch >= N_PATCH_TOTAL) return;          // wave-uniform (never taken)

    const int b   = patch / (OUT_HW * OUT_HW);
    const int rem = patch - b * (OUT_HW * OUT_HW);
    const int oy  = rem / OUT_HW;
    const int ox  = rem - oy * OUT_HW;

    const float* xp = x + b * 16384 + (oy * 2) * 128 + (ox * 2);

    // ---- Product-state construction: state after RX encode + Rot(l=0) layer.
    // Per qubit q: (alpha,beta) = first column of Rot(l0,q)*RX(a_q):
    //   alpha = ( c*R0 + s*R3,  c*R1 - s*R2 )
    //   beta  = ( c*R4 + s*R7,  c*R5 - s*R6 )   [c=cos(a/2), s=sin(a/2)]
    // amp(p) = prod_q (bit_q(p) ? beta_q : alpha_q).
    float ar[8], ai[8];
    {
        float Lr = 1.0f, Li = 0.0f;              // lane factor (qubits 3..8)
        #pragma unroll
        for (int q = 3; q < 9; ++q) {
            const float a = xp[(q / 3) * 128 + (q % 3)];
            float s, c;
            __sincosf(0.5f * a, &s, &c);
            const float* R = rot + 8 * q;
            const float alr = c*R[0] + s*R[3], ali = c*R[1] - s*R[2];
            const float ber = c*R[4] + s*R[7], bei = c*R[5] - s*R[6];
            const int bit = (lane >> (q - 3)) & 1;
            const float fr = bit ? ber : alr;
            const float fi = bit ? bei : ali;
            const float nr = Lr*fr - Li*fi;
            const float ni = Lr*fi + Li*fr;
            Lr = nr; Li = ni;
        }
        float alr[3], ali_[3], ber[3], bei[3];
        #pragma unroll
        for (int q = 0; q < 3; ++q) {
            const float a = xp[(q / 3) * 128 + (q % 3)];
            float s, c;
            __sincosf(0.5f * a, &s, &c);
            const float* R = rot + 8 * q;
            alr[q] = c*R[0] + s*R[3]; ali_[q] = c*R[1] - s*R[2];
            ber[q] = c*R[4] + s*R[7]; bei[q] = c*R[5] - s*R[6];
        }
        // c01[j] = f0(j&1) * f1(j&2), j=0..3
        float c01r[4], c01i[4];
        #pragma unroll
        for (int j = 0; j < 4; ++j) {
            const float f0r = (j & 1) ? ber[0] : alr[0];
            const float f0i = (j & 1) ? bei[0] : ali_[0];
            const float f1r = (j & 2) ? ber[1] : alr[1];
            const float f1i = (j & 2) ? bei[1] : ali_[1];
            c01r[j] = f0r*f1r - f0i*f1i;
            c01i[j] = f0r*f1i + f0i*f1r;
        }
        #pragma unroll
        for (int r = 0; r < 8; ++r) {
            const float f2r = (r & 4) ? ber[2] : alr[2];
            const float f2i = (r & 4) ? bei[2] : ali_[2];
            const float gr = c01r[r & 3]*f2r - c01i[r & 3]*f2i;
            const float gi = c01r[r & 3]*f2i + c01i[r & 3]*f2r;
            ar[r] = gr*Lr - gi*Li;
            ai[r] = gr*Li + gi*Lr;
        }
    }

    // ring r=1 after layer 1
    ring1(ar, ai, lane);
    {   // Layer 2: Rot(l=1), ring r=2
        const float* m = rot + 72;
        APPLY_ROT(0) APPLY_ROT(1) APPLY_ROT(2) APPLY_ROT(3) APPLY_ROT(4)
        APPLY_ROT(5) APPLY_ROT(6) APPLY_ROT(7) APPLY_ROT(8)
        ring2(ar, ai, lane);
    }
    {   // Layer 3: Rot(l=0), ring r=1
        const float* m = rot;
        APPLY_ROT(0) APPLY_ROT(1) APPLY_ROT(2) APPLY_ROT(3) APPLY_ROT(4)
        APPLY_ROT(5) APPLY_ROT(6) APPLY_ROT(7) APPLY_ROT(8)
        ring1(ar, ai, lane);
    }
    {   // Layer 4: Rot(l=1). Final ring r=2 is absorbed into measurement.
        const float* m = rot + 72;
        APPLY_ROT(0) APPLY_ROT(1) APPLY_ROT(2) APPLY_ROT(3) APPLY_ROT(4)
        APPLY_ROT(5) APPLY_ROT(6) APPLY_ROT(7) APPLY_ROT(8)
    }

    // ---- Measurement with ring2 absorbed: e_q = sum_p (-1)^{parity(p & w_q)} |amp_p|^2
    // w = {0x0AB,0x157,0x005,0x00A,0x015,0x02A,0x055,0x0AA,0x155}
    // (row-update w_t ^= w_c over ring2; cross-checked vs Heisenberg pull-back)
    float p[8];
    #pragma unroll
    for (int r = 0; r < 8; ++r) p[r] = ar[r]*ar[r] + ai[r]*ai[r];

    // 4 signed register sums (reg masks 3, 7, 5, 2)
    const float S3 = (p[0]+p[3]+p[4]+p[7]) - (p[1]+p[2]+p[5]+p[6]);
    const float S7 = (p[0]+p[3]+p[5]+p[6]) - (p[1]+p[2]+p[4]+p[7]);
    const float S5 = (p[0]+p[2]+p[5]+p[7]) - (p[1]+p[3]+p[4]+p[6]);
    const float S2 = (p[0]+p[1]+p[4]+p[5]) - (p[2]+p[3]+p[6]+p[7]);

    // lane parity bits
    const int b0 = lane & 1, b1 = (lane >> 1) & 1, b2 = (lane >> 2) & 1;
    const int b3 = (lane >> 3) & 1, b4 = (lane >> 4) & 1, b5 = (lane >> 5) & 1;
    const int p05 = b0 ^ b2, p0A = b1 ^ b3;
    const int p15 = p05 ^ b4, p2A = p0A ^ b5;

    float e[9];
    e[0] = sgn_apply(S3, p15);   // w0 = 0x0AB: reg 3, lane 0x15
    e[1] = sgn_apply(S7, p2A);   // w1 = 0x157: reg 7, lane 0x2A
    e[2] = S5;                   // w2 = 0x005: reg 5
    e[3] = sgn_apply(S2, b0);    // w3 = 0x00A: reg 2, lane 1
    e[4] = sgn_apply(S5, b1);    // w4 = 0x015: reg 5, lane 2
    e[5] = sgn_apply(S2, p05);   // w5 = 0x02A: reg 2, lane 5
    e[6] = sgn_apply(S5, p0A);   // w6 = 0x055: reg 5, lane 0xA
    e[7] = sgn_apply(S2, p15);   // w7 = 0x0AA: reg 2, lane 0x15
    e[8] = sgn_apply(S5, p2A);   // w8 = 0x155: reg 5, lane 0x2A

    // Butterfly reduce across the 64 lanes
    #pragma unroll
    for (int q = 0; q < 9; ++q) e[q] += shflx<1>(e[q], lane);
    #pragma unroll
    for (int q = 0; q < 9; ++q) e[q] += shflx<2>(e[q], lane);
    #pragma unroll
    for (int q = 0; q < 9; ++q) e[q] += shflx<4>(e[q], lane);
    #pragma unroll
    for (int q = 0; q < 9; ++q) e[q] += shflx<8>(e[q], lane);
    #pragma unroll
    for (int q = 0; q < 9; ++q) e[q] += shflx<16>(e[q], lane);
    #pragma unroll
    for (int q = 0; q < 9; ++q) e[q] += shflx<32>(e[q], lane);

    // lanes 0..8 each store one channel (single predicated store)
    float v = e[0];
    v = (lane == 1) ? e[1] : v;
    v = (lane == 2) ? e[2] : v;
    v = (lane == 3) ? e[3] : v;
    v = (lane == 4) ? e[4] : v;
    v = (lane == 5) ? e[5] : v;
    v = (lane == 6) ? e[6] : v;
    v = (lane == 7) ? e[7] : v;
    v = (lane == 8) ? e[8] : v;
    if (lane < 9) {
        out[(b * 9 + lane) * (OUT_HW * OUT_HW) + oy * OUT_HW + ox] = v;
    }
}

} // anonymous namespace

extern "C" void kernel_launch(void* const* d_in, const int* in_sizes, int n_in,
                              void* d_out, int out_size, void* d_ws, size_t ws_size,
                              hipStream_t stream)
{
    const float* x = (const float*)d_in[0];   // (8,1,128,128) float32
    const float* w = (const float*)d_in[1];   // (2,9,3) float32
    float* rot = (float*)d_ws;                // 144 floats scratch
    float* out = (float*)d_out;               // (8,9,63,63) float32

    rot_precomp_kernel<<<1, 64, 0, stream>>>(w, rot);
    qconv_kernel<<<N_PATCH_TOTAL / PPB, PPB * 64, 0, stream>>>(x, rot, out);
}

// Round 5
// 151.800 us; speedup vs baseline: 2.8190x; 1.8516x over previous
//
#include <hip/hip_runtime.h>

// Quanvolution: 8x1x128x128 input, K=3, STRIDE=2 -> 63x63 patches per image,
// 9-qubit statevector sim per patch, output (8, 9, 63, 63) PauliZ expvals.
//
// Layout: one wave (64 lanes) per patch. 512 amplitudes -> 8 complex per lane.
// Amplitude index bits: [2:0] = register slot r, [8:3] = lane id.
//
// R5 changes vs R4 (passed, 281 us bench / 236 us rocprof):
//  - R4's __launch_bounds__(256,8) forced VGPR=32 -> 874 MB/dispatch scratch
//    spill (46% HBM peak). Relax to (256,6): VGPR cap ~85, no spill, 6+
//    waves/SIMD.
//  - Lane-ctrl/reg-tgt CNOT stragglers (cnot<8,0> x2, cnot<7,0>, cnot<8,1>)
//    fused into the FOLLOWING Rot layer as per-lane column swaps:
//    G(q)*CNOT(c,q) == (columns-swapped G on lanes with bit c set)(q) applied
//    to the pre-CNOT state; CNOT(8,1) commutes with Rot(q0) so the reorder is
//    legal. Saves ~96 VALU and 4 serial steps.

namespace {

constexpr int OUT_HW = 63;
constexpr int PPB = 4;                                  // waves (patches) per block
constexpr int N_PATCH_TOTAL = 8 * OUT_HW * OUT_HW;      // 31752 == 7938 * 4

__device__ __forceinline__ float bperm(int addr_bytes, float v) {
    return __int_as_float(__builtin_amdgcn_ds_bpermute(addr_bytes, __float_as_int(v)));
}

// xor-shuffle across lanes: ds_swizzle for mask<32 (no addr VGPR), bpermute for 32
template<int M>
__device__ __forceinline__ float shflx(float v, int lane) {
    if constexpr (M < 32)
        return __int_as_float(__builtin_amdgcn_ds_swizzle(__float_as_int(v),
                                                          0x1F | (M << 10)));
    else
        return bperm((lane << 2) ^ 128, v);
}

// General 2x2 unitary on qubit Q. Coefficients may be per-lane (col-swapped).
template<int Q>
__device__ __forceinline__ void gate1q(float (&ar)[8], float (&ai)[8], int lane,
                                       float u00r, float u00i, float u01r, float u01i,
                                       float u10r, float u10i, float u11r, float u11i)
{
    if constexpr (Q < 3) {
        constexpr int qm = 1 << Q;
        #pragma unroll
        for (int r = 0; r < 8; ++r) {
            if (!(r & qm)) {
                const int r1 = r | qm;
                const float xr = ar[r],  xi = ai[r];
                const float yr = ar[r1], yi = ai[r1];
                ar[r]  = u00r*xr - u00i*xi + u01r*yr - u01i*yi;
                ai[r]  = u00r*xi + u00i*xr + u01r*yi + u01i*yr;
                ar[r1] = u10r*xr - u10i*xi + u11r*yr - u11i*yi;
                ai[r1] = u10r*xi + u10i*xr + u11r*yi + u11i*yr;
            }
        }
    } else {
        constexpr int lm = 1 << (Q - 3);
        const int bit = (lane >> (Q - 3)) & 1;
        const float csr = bit ? u11r : u00r;   // coefficient of self
        const float csi = bit ? u11i : u00i;
        const float cpr = bit ? u10r : u01r;   // coefficient of partner
        const float cpi = bit ? u10i : u01i;
        #pragma unroll
        for (int r = 0; r < 8; ++r) {
            const float br = shflx<lm>(ar[r], lane);
            const float bi = shflx<lm>(ai[r], lane);
            const float nr = csr*ar[r] - csi*ai[r] + cpr*br - cpi*bi;
            const float ni = csr*ai[r] + csi*ar[r] + cpr*bi + cpi*br;
            ar[r] = nr; ai[r] = ni;
        }
    }
}

// CNOT control C target T (reg-reg rename only; others are fused/absorbed).
template<int C, int T>
__device__ __forceinline__ void cnot(float (&ar)[8], float (&ai)[8], int lane)
{
    static_assert(C < 3 && T < 3, "only reg-reg CNOTs instantiated");
    constexpr int cm = 1 << C, tm = 1 << T;
    #pragma unroll
    for (int r = 0; r < 8; ++r) {
        if ((r & cm) && !(r & tm)) {
            const int r1 = r | tm;
            const float tr = ar[r], ti = ai[r];
            ar[r] = ar[r1]; ai[r] = ai[r1];
            ar[r1] = tr;    ai[r1] = ti;
        }
    }
}

// Ring r=1 minus its trailing cnot(8,0) (deferred as column swap into the
// next Rot layer's q0): (0,1)(1,2) reg renames; (2,3)..(7,8) compose to
//   src_lane = lane ^ ((lane & 31) << 1) ^ bit2(reg).
__device__ __forceinline__ void ring1_partial(float (&ar)[8], float (&ai)[8], int lane)
{
    cnot<0,1>(ar, ai, lane);
    cnot<1,2>(ar, ai, lane);
    const int sA = (lane ^ ((lane & 31) << 1)) << 2;
    const int sB = sA ^ 4;                  // ^ lane bit0 (regs with bit2 set)
    #pragma unroll
    for (int r = 0; r < 8; ++r) {
        const int a = (r & 4) ? sB : sA;
        ar[r] = bperm(a, ar[r]);
        ai[r] = bperm(a, ai[r]);
    }
}

// Ring r=2 minus its trailing cnot(7,0),cnot(8,1) (deferred as column swaps):
// (0,2) reg rename; (1,3)..(6,8) compose to
//   src_lane = lane ^ ((lane & 15) << 2) ^ bit1(reg) ^ (bit2(reg)<<1).
__device__ __forceinline__ void ring2_partial(float (&ar)[8], float (&ai)[8], int lane)
{
    cnot<0,2>(ar, ai, lane);
    const int s0 = (lane ^ ((lane & 15) << 2)) << 2;
    #pragma unroll
    for (int r = 0; r < 8; ++r) {
        const int a = s0 ^ (((r >> 1) & 1) << 2) ^ (((r >> 2) & 1) << 3);
        ar[r] = bperm(a, ar[r]);
        ai[r] = bperm(a, ai[r]);
    }
}

// Precompute the 18 Rot matrices (weights shared across all patches).
// rot[(l*9+q)*8 + {0..7}] = u00.re,u00.im,u01.re,u01.im,u10.re,u10.im,u11.re,u11.im
__global__ void rot_precomp_kernel(const float* __restrict__ w, float* __restrict__ rot)
{
    const int i = threadIdx.x;
    if (i >= 18) return;
    const float phi = w[i*3 + 0], theta = w[i*3 + 1], omega = w[i*3 + 2];
    const float ct = cosf(0.5f * theta), st = sinf(0.5f * theta);
    const float apo = 0.5f * (phi + omega), amo = 0.5f * (phi - omega);
    const float ca = cosf(apo), sa = sinf(apo);
    const float cm = cosf(amo), sm = sinf(amo);
    float* m = rot + i * 8;
    m[0] =  ca * ct; m[1] = -sa * ct;   // u00 = e^{-i(phi+omega)/2} cos(th/2)
    m[2] = -cm * st; m[3] = -sm * st;   // u01 = -e^{+i(phi-omega)/2} sin(th/2)
    m[4] =  cm * st; m[5] = -sm * st;   // u10 = e^{-i(phi-omega)/2} sin(th/2)
    m[6] =  ca * ct; m[7] =  sa * ct;   // u11 = e^{+i(phi+omega)/2} cos(th/2)
}

#define APPLY_ROT(q) gate1q<q>(ar, ai, lane, m[8*(q)+0], m[8*(q)+1], m[8*(q)+2], m[8*(q)+3], \
                                             m[8*(q)+4], m[8*(q)+5], m[8*(q)+6], m[8*(q)+7]);

// Rot with a deferred CNOT absorbed: columns swapped on lanes where sw is set.
#define APPLY_ROT_SW(q, sw) { \
    const float* R = m + 8*(q); \
    const float v00r = (sw) ? R[2] : R[0], v00i = (sw) ? R[3] : R[1]; \
    const float v01r = (sw) ? R[0] : R[2], v01i = (sw) ? R[1] : R[3]; \
    const float v10r = (sw) ? R[6] : R[4], v10i = (sw) ? R[7] : R[5]; \
    const float v11r = (sw) ? R[4] : R[6], v11i = (sw) ? R[5] : R[7]; \
    gate1q<q>(ar, ai, lane, v00r, v00i, v01r, v01i, v10r, v10i, v11r, v11i); }

// sign-apply: v * (-1)^par  (par in {0,1})
__device__ __forceinline__ float sgn_apply(float v, int par) {
    return __int_as_float(__float_as_int(v) ^ (par << 31));
}

__global__ __launch_bounds__(PPB * 64, 6) void qconv_kernel(
    const float* __restrict__ x,      // (8, 1, 128, 128)
    const float* __restrict__ rot,    // (2, 9, 8) precomputed Rot matrices
    float* __restrict__ out)          // (8, 9, 63, 63)
{
    const int lane  = threadIdx.x & 63;
    const int wv    = threadIdx.x >> 6;
    const int patch = blockIdx.x * PPB + wv;
    if (patch >= N_PATCH_TOTAL) return;          // wave-uniform (never taken)

    const int b   = patch / (OUT_HW * OUT_HW);
    const int rem = patch - b * (OUT_HW * OUT_HW);
    const int oy  = rem / OUT_HW;
    const int ox  = rem - oy * OUT_HW;

    const float* xp = x + b * 16384 + (oy * 2) * 128 + (ox * 2);

    // ---- Product-state construction: state after RX encode + Rot(l=0) layer.
    // Per qubit q: (alpha,beta) = first column of Rot(l0,q)*RX(a_q).
    float ar[8], ai[8];
    {
        float Lr = 1.0f, Li = 0.0f;              // lane factor (qubits 3..8)
        #pragma unroll
        for (int q = 3; q < 9; ++q) {
            const float a = xp[(q / 3) * 128 + (q % 3)];
            float s, c;
            __sincosf(0.5f * a, &s, &c);
            const float* R = rot + 8 * q;
            const float alr = c*R[0] + s*R[3], ali = c*R[1] - s*R[2];
            const float ber = c*R[4] + s*R[7], bei = c*R[5] - s*R[6];
            const int bit = (lane >> (q - 3)) & 1;
            const float fr = bit ? ber : alr;
            const float fi = bit ? bei : ali;
            const float nr = Lr*fr - Li*fi;
            const float ni = Lr*fi + Li*fr;
            Lr = nr; Li = ni;
        }
        float alr[3], ali_[3], ber[3], bei[3];
        #pragma unroll
        for (int q = 0; q < 3; ++q) {
            const float a = xp[(q / 3) * 128 + (q % 3)];
            float s, c;
            __sincosf(0.5f * a, &s, &c);
            const float* R = rot + 8 * q;
            alr[q] = c*R[0] + s*R[3]; ali_[q] = c*R[1] - s*R[2];
            ber[q] = c*R[4] + s*R[7]; bei[q] = c*R[5] - s*R[6];
        }
        float c01r[4], c01i[4];
        #pragma unroll
        for (int j = 0; j < 4; ++j) {
            const float f0r = (j & 1) ? ber[0] : alr[0];
            const float f0i = (j & 1) ? bei[0] : ali_[0];
            const float f1r = (j & 2) ? ber[1] : alr[1];
            const float f1i = (j & 2) ? bei[1] : ali_[1];
            c01r[j] = f0r*f1r - f0i*f1i;
            c01i[j] = f0r*f1i + f0i*f1r;
        }
        #pragma unroll
        for (int r = 0; r < 8; ++r) {
            const float f2r = (r & 4) ? ber[2] : alr[2];
            const float f2i = (r & 4) ? bei[2] : ali_[2];
            const float gr = c01r[r & 3]*f2r - c01i[r & 3]*f2i;
            const float gi = c01r[r & 3]*f2i + c01i[r & 3]*f2r;
            ar[r] = gr*Lr - gi*Li;
            ai[r] = gr*Li + gi*Lr;
        }
    }

    const bool b4 = ((lane >> 4) & 1) != 0;   // amp-index bit 7
    const bool b5 = ((lane >> 5) & 1) != 0;   // amp-index bit 8

    // ring r=1 after layer 1 (cnot(8,0) deferred into L2's q0)
    ring1_partial(ar, ai, lane);
    {   // Layer 2: Rot(l=1); q0 absorbs CNOT(8,0) (col swap on b5)
        const float* m = rot + 72;
        APPLY_ROT_SW(0, b5)
        APPLY_ROT(1) APPLY_ROT(2) APPLY_ROT(3) APPLY_ROT(4)
        APPLY_ROT(5) APPLY_ROT(6) APPLY_ROT(7) APPLY_ROT(8)
        ring2_partial(ar, ai, lane);   // cnot(7,0),(8,1) deferred into L3
    }
    {   // Layer 3: Rot(l=0); q0 absorbs CNOT(7,0) (b4), q1 absorbs CNOT(8,1) (b5)
        const float* m = rot;
        APPLY_ROT_SW(0, b4)
        APPLY_ROT_SW(1, b5)
        APPLY_ROT(2) APPLY_ROT(3) APPLY_ROT(4)
        APPLY_ROT(5) APPLY_ROT(6) APPLY_ROT(7) APPLY_ROT(8)
        ring1_partial(ar, ai, lane);   // cnot(8,0) deferred into L4
    }
    {   // Layer 4: Rot(l=1); q0 absorbs CNOT(8,0) (b5). Final ring2 absorbed
        // into the measurement masks below.
        const float* m = rot + 72;
        APPLY_ROT_SW(0, b5)
        APPLY_ROT(1) APPLY_ROT(2) APPLY_ROT(3) APPLY_ROT(4)
        APPLY_ROT(5) APPLY_ROT(6) APPLY_ROT(7) APPLY_ROT(8)
    }

    // ---- Measurement with final ring2 absorbed:
    // e_q = sum_p (-1)^{parity(p & w_q)} |amp_p|^2,
    // w = {0x0AB,0x157,0x005,0x00A,0x015,0x02A,0x055,0x0AA,0x155}
    float p[8];
    #pragma unroll
    for (int r = 0; r < 8; ++r) p[r] = ar[r]*ar[r] + ai[r]*ai[r];

    const float S3 = (p[0]+p[3]+p[4]+p[7]) - (p[1]+p[2]+p[5]+p[6]);
    const float S7 = (p[0]+p[3]+p[5]+p[6]) - (p[1]+p[2]+p[4]+p[7]);
    const float S5 = (p[0]+p[2]+p[5]+p[7]) - (p[1]+p[3]+p[4]+p[6]);
    const float S2 = (p[0]+p[1]+p[4]+p[5]) - (p[2]+p[3]+p[6]+p[7]);

    const int c0 = lane & 1, c1 = (lane >> 1) & 1, c2 = (lane >> 2) & 1;
    const int c3 = (lane >> 3) & 1, c4 = (lane >> 4) & 1, c5 = (lane >> 5) & 1;
    const int p05 = c0 ^ c2, p0A = c1 ^ c3;
    const int p15 = p05 ^ c4, p2A = p0A ^ c5;

    float e[9];
    e[0] = sgn_apply(S3, p15);   // w0 = 0x0AB: reg 3, lane 0x15
    e[1] = sgn_apply(S7, p2A);   // w1 = 0x157: reg 7, lane 0x2A
    e[2] = S5;                   // w2 = 0x005: reg 5
    e[3] = sgn_apply(S2, c0);    // w3 = 0x00A: reg 2, lane 1
    e[4] = sgn_apply(S5, c1);    // w4 = 0x015: reg 5, lane 2
    e[5] = sgn_apply(S2, p05);   // w5 = 0x02A: reg 2, lane 5
    e[6] = sgn_apply(S5, p0A);   // w6 = 0x055: reg 5, lane 0xA
    e[7] = sgn_apply(S2, p15);   // w7 = 0x0AA: reg 2, lane 0x15
    e[8] = sgn_apply(S5, p2A);   // w8 = 0x155: reg 5, lane 0x2A

    // Butterfly reduce across the 64 lanes
    #pragma unroll
    for (int q = 0; q < 9; ++q) e[q] += shflx<1>(e[q], lane);
    #pragma unroll
    for (int q = 0; q < 9; ++q) e[q] += shflx<2>(e[q], lane);
    #pragma unroll
    for (int q = 0; q < 9; ++q) e[q] += shflx<4>(e[q], lane);
    #pragma unroll
    for (int q = 0; q < 9; ++q) e[q] += shflx<8>(e[q], lane);
    #pragma unroll
    for (int q = 0; q < 9; ++q) e[q] += shflx<16>(e[q], lane);
    #pragma unroll
    for (int q = 0; q < 9; ++q) e[q] += shflx<32>(e[q], lane);

    // lanes 0..8 each store one channel (single predicated store)
    float v = e[0];
    v = (lane == 1) ? e[1] : v;
    v = (lane == 2) ? e[2] : v;
    v = (lane == 3) ? e[3] : v;
    v = (lane == 4) ? e[4] : v;
    v = (lane == 5) ? e[5] : v;
    v = (lane == 6) ? e[6] : v;
    v = (lane == 7) ? e[7] : v;
    v = (lane == 8) ? e[8] : v;
    if (lane < 9) {
        out[(b * 9 + lane) * (OUT_HW * OUT_HW) + oy * OUT_HW + ox] = v;
    }
}

} // anonymous namespace

extern "C" void kernel_launch(void* const* d_in, const int* in_sizes, int n_in,
                              void* d_out, int out_size, void* d_ws, size_t ws_size,
                              hipStream_t stream)
{
    const float* x = (const float*)d_in[0];   // (8,1,128,128) float32
    const float* w = (const float*)d_in[1];   // (2,9,3) float32
    float* rot = (float*)d_ws;                // 144 floats scratch
    float* out = (float*)d_out;               // (8,9,63,63) float32

    rot_precomp_kernel<<<1, 64, 0, stream>>>(w, rot);
    qconv_kernel<<<N_PATCH_TOTAL / PPB, PPB * 64, 0, stream>>>(x, rot, out);
}